// Round 5
// baseline (209.012 us; speedup 1.0000x reference)
//
#include <hip/hip_runtime.h>
#include <stdint.h>

// Problem constants (fixed by setup_inputs: B=2,H=16,N=2048,D=128), f32 in/out.
#define NN 2048
#define DD 128
#define BHH 32
#define QT 64   // queries per block (32 per wave, both teams cover same 64 q)
#define KT 64   // keys per K tile

typedef short v8s __attribute__((ext_vector_type(8)));   // 8 bf16 (raw bits)
typedef short v4s __attribute__((ext_vector_type(4)));   // 4 bf16
typedef float v4f __attribute__((ext_vector_type(4)));
typedef float v16f __attribute__((ext_vector_type(16)));
typedef unsigned int u32;
typedef u32 u32x2 __attribute__((ext_vector_type(2)));
typedef u32 u32x4 __attribute__((ext_vector_type(4)));

__device__ __forceinline__ unsigned short f2bf(float x) {
  unsigned u = __builtin_bit_cast(unsigned, x);
  u += 0x7fffu + ((u >> 16) & 1u);   // RNE
  return (unsigned short)(u >> 16);
}

__device__ __forceinline__ v8s cvt8(const float* __restrict__ p) {
  v8s r;
#pragma unroll
  for (int j = 0; j < 8; j++) r[j] = (short)f2bf(p[j]);
  return r;
}

// v_cvt_pk_bf16_f32: 2 f32 -> packed 2x bf16 (RNE), single VALU op.
__device__ __forceinline__ u32 pk2(float a, float b) {
  u32 r;
  asm("v_cvt_pk_bf16_f32 %0, %1, %2" : "=v"(r) : "v"(a), "v"(b));
  return r;
}

// Fused prep, one dispatch. grid=(32,2,64):
//  z <  32: Vfrag[bh][ktab][nc][lane] = MFMA-B-fragment-ordered bf16 V:
//           frag(ktab,nc) lane l elem j = V[ktab*16+(l>>5)*8+j][nc*32+(l&31)]
//           (1KB frags; attn PV loads are single coalesced 1KB reads)
//  z >= 32: Kb[bh=z-32] chunk = bf16(K chunk), flat copy, 16 elems/thread
__global__ __launch_bounds__(256) void prep(const float* __restrict__ K, const float* __restrict__ V,
                     unsigned short* __restrict__ Kb, unsigned short* __restrict__ Vt) {
  const int z = blockIdx.z;
  const int tid = threadIdx.x;
  if (z >= BHH) {
    const int bh = z - BHH;
    const int chunk = blockIdx.y * 32 + blockIdx.x;           // 0..63
    size_t base = (size_t)bh * NN * DD + (size_t)chunk * 4096 + (size_t)tid * 16;
    v4f f0 = *(const v4f*)(K + base);
    v4f f1 = *(const v4f*)(K + base + 4);
    v4f f2 = *(const v4f*)(K + base + 8);
    v4f f3 = *(const v4f*)(K + base + 12);
    u32x4 w0 = { pk2(f0[0], f0[1]), pk2(f0[2], f0[3]), pk2(f1[0], f1[1]), pk2(f1[2], f1[3]) };
    u32x4 w1 = { pk2(f2[0], f2[1]), pk2(f2[2], f2[3]), pk2(f3[0], f3[1]), pk2(f3[2], f3[3]) };
    *(u32x4*)(Kb + base) = w0;
    *(u32x4*)(Kb + base + 8) = w1;
    return;
  }
  __shared__ __align__(16) unsigned short t[64 * 68];  // [dloc][nloc], stride 68
  const int bh = z;
  const int n0b = blockIdx.x, d0b = blockIdx.y;        // 64-blocks
  const int c16 = tid & 15, r4 = tid >> 4;
  // phase1: 4x4 f32 sub-block (rows n, cols d), transpose in-register
  const float* src = V + ((size_t)bh * NN + n0b * 64 + r4 * 4) * DD + d0b * 64 + c16 * 4;
  v4f f0 = *(const v4f*)(src);
  v4f f1 = *(const v4f*)(src + DD);
  v4f f2 = *(const v4f*)(src + 2 * DD);
  v4f f3 = *(const v4f*)(src + 3 * DD);
#pragma unroll
  for (int j = 0; j < 4; j++) {
    u32x2 w = { pk2(f0[j], f1[j]), pk2(f2[j], f3[j]) };   // n-order r4*4..+3
    *(u32x2*)(t + (c16 * 4 + j) * 68 + r4 * 4) = w;       // t[d][n] = V[n][d]
  }
  __syncthreads();
  // phase2: emit 8 fragments (4 ktab x 2 nc), coalesced 1KB global stores
  unsigned short* Vfb = Vt + (size_t)bh * (512u * 512);   // 128*4*512 shorts/bh
#pragma unroll
  for (int p = 0; p < 2; p++) {
    const int fid = p * 4 + (tid >> 6);       // 0..7
    const int ktl = fid >> 1, ncl = fid & 1;
    const int lane = tid & 63;
    const int dloc = ncl * 32 + (lane & 31);
    const int nloc = ktl * 16 + (lane >> 5) * 8;
    v4s x0 = *(const v4s*)(t + dloc * 68 + nloc);
    v4s x1 = *(const v4s*)(t + dloc * 68 + nloc + 4);
    v8s o = { x0[0], x0[1], x0[2], x0[3], x1[0], x1[1], x1[2], x1[3] };
    const size_t fi = (size_t)(n0b * 4 + ktl) * 4 + (d0b * 2 + ncl);
    *(v8s*)(Vfb + fi * 512 + (size_t)lane * 8) = o;
  }
}

// Flash-style sink+sliding-window attention, f32 in/out, bf16 MFMA compute.
// R5: key-split teams. r3/r4 post-mortem: q-ownership caps waves at 8/CU
// (32q/wave) and r4 ran at 6 -> latency-bound (MfmaUtil 13% == offered load).
// Plain-exp2 softmax (no running max) => partials over disjoint key ranges
// merge by ADDITION. Block = 256 thr = 2 teams x 2 waves; teams take
// even/odd K-tiles of the same job; in-LDS merge at the end.
//  - K: staged to per-team 16KB LDS (r4-proven layout), prefetch dist 2*KT.
//  - V: NO LDS. prep emits fragment-ordered Vfrag; PV B-frags are coalesced
//    1KB global loads issued a QK+softmax (~600cyc) ahead of use (L2-resident).
//  - P in registers via swapped QK^T + cvt_pk + permlane32_swap (r4-proven).
//  - lsum tree-reassociated (was 32x serial f32 adds).
// Jobs: same 24/bh x 17-tile-unit mapping; sink16 runs on team1 (which has
// 8 window tiles vs team0's 9). Dummy iterations keep barrier counts equal.
// mfma_f32_32x32x16_bf16 layouts: A: lane holds A[m=lane&31][k=(lane>>5)*8+j]
// B: B[k=(lane>>5)*8+j][n=lane&31]; C/D: D[row=(reg&3)+8*(reg>>2)+4*(lane>>5)]
// [col=lane&31]  (m74/m101-verified mapping).
template <bool PREPPED>
__global__ __launch_bounds__(256, 2) void attn(
    const float* __restrict__ Q,
    const float* __restrict__ Kf, const unsigned short* __restrict__ Kb,
    const unsigned short* __restrict__ Vfr, const float* __restrict__ Vf,
    const int* __restrict__ nsp, const int* __restrict__ wsp,
    float* __restrict__ O) {
  const int ns = nsp[0], win = wsp[0];
  const int x = blockIdx.x;              // 0..767
  const int xcd = x & 7, slot = x >> 3;  // slot 0..95
  const int bh = xcd + 8 * (slot / 24);
  const int jobid = slot % 24;           // 0..23
  int qis[2], njobs;
  if (jobid < 16) { njobs = 1; qis[0] = 31 - jobid; qis[1] = 0; }
  else { int p = jobid - 16; njobs = 2; qis[0] = 15 - p; qis[1] = p; }

  const int tid = threadIdx.x;
  const int wave = tid >> 6;   // 0..3
  const int team = wave >> 1;  // key-split half
  const int wv = wave & 1;     // wave within team -> q rows wv*32..+31
  const int l = tid & 63;
  const int m = l & 31;
  const int hi = l >> 5;
  const int rbase = 4 * hi;

  __shared__ __align__(16) unsigned short Kl[2][16 * 512];  // 2 x 16 KB
  __shared__ float Ls[128];

  const float csc = 0.088388347648318447f * 1.4426950408889634f;  // 1/sqrt(128)*log2(e)

  const size_t kK = ((size_t)bh * NN + wv * 32 + m) * DD + hi * 8;  // K stage src
  const unsigned short* Vfb = Vfr + (size_t)bh * (512u * 512);

  // P C-layout -> PV A-frag via cvt_pk + permlane32_swap (all-register)
  auto mkpa = [&](float a0, float a1, float a2, float a3,
                  float b0, float b1, float b2, float b3) -> v8s {
    u32x2 r02 = __builtin_amdgcn_permlane32_swap(pk2(a0, a1), pk2(b0, b1), false, false);
    u32x2 r13 = __builtin_amdgcn_permlane32_swap(pk2(a2, a3), pk2(b2, b3), false, false);
    u32x4 pw = { r02[0], r13[0], r02[1], r13[1] };
    return __builtin_bit_cast(v8s, pw);
  };

  for (int ji = 0; ji < njobs; ji++) {
    const int q0 = qis[ji] * QT;
    const int qrow0w = q0 + wv * 32;  // this wave's 32 query rows
    const int qi = qrow0w + m;        // this lane's query (S^T col)

    // Q B-frags, pre-scaled: lane holds Q[qi][kc*16 + hi*8 + j]*csc
    v8s qf[8];
    {
      const float* qb = Q + ((size_t)bh * NN + qi) * DD + hi * 8;
#pragma unroll
      for (int kc = 0; kc < 8; kc++) {
        v8s r;
#pragma unroll
        for (int e = 0; e < 8; e++) r[e] = (short)f2bf(qb[kc * 16 + e] * csc);
        qf[kc] = r;
      }
    }

    float lsum = 0.f;
    v16f oa[4];
#pragma unroll
    for (int nc = 0; nc < 4; nc++) oa[nc] = (v16f)(0.f);

    // ---- tile range (contiguous, r3-verified) ----
    const int wstart = q0 - win + 1;
    const bool sink16 = (wstart > KT - 1) && (ns <= 16);
    const int kb_lo = sink16 ? ((wstart >> 6) << 6) : 0;
    const int kb_hi = q0 + QT;
    const int ntiles = (kb_hi - kb_lo) >> 6;
    const int T = (ntiles + 1) >> 1;   // iterations per team (dummy-padded)

    // K prefetch regs: wave stages 8 frags (rows wv*32+m of the team's tile)
    v8s kst[8];
    auto stage_load = [&](int kb) {
#pragma unroll
      for (int i = 0; i < 8; i++) {
        if constexpr (PREPPED)
          kst[i] = *(const v8s*)(Kb + kK + (size_t)kb * DD + i * 16);
        else
          kst[i] = cvt8(Kf + kK + (size_t)kb * DD + i * 16);
      }
    };

    const int kb0 = kb_lo + team * KT;
    if (kb0 < kb_hi) stage_load(kb0);

    if (sink16 && team == 1) {
      // sink tile: keys 0..31, one 32x32 S block (keys >= ns masked)
      v8s kf0[8];
      const size_t g0 = ((size_t)bh * NN + m) * DD + hi * 8;
#pragma unroll
      for (int kc = 0; kc < 8; kc++)
        kf0[kc] = PREPPED ? *(const v8s*)(Kb + g0 + kc * 16) : cvt8(Kf + g0 + kc * 16);
      v16f s = (v16f)(0.f);
#pragma unroll
      for (int kc = 0; kc < 8; kc++)
        s = __builtin_amdgcn_mfma_f32_32x32x16_bf16(kf0[kc], qf[kc], s, 0, 0, 0);
#pragma unroll
      for (int reg = 0; reg < 16; reg++) {
        const int kj = (reg & 3) + 8 * (reg >> 2) + rbase;
        const bool valid = (kj < ns) && (kj <= qi);
        s[reg] = valid ? __builtin_amdgcn_exp2f(s[reg]) : 0.f;
      }
      lsum += (((s[0] + s[1]) + (s[2] + s[3])) + ((s[4] + s[5]) + (s[6] + s[7])))
            + (((s[8] + s[9]) + (s[10] + s[11])) + ((s[12] + s[13]) + (s[14] + s[15])));
      // keys 16..31 masked (ns<=16): only kt0 PV needed
      v8s pa = mkpa(s[0], s[1], s[2], s[3], s[4], s[5], s[6], s[7]);
#pragma unroll
      for (int nc = 0; nc < 4; nc++) {
        v8s vf;
        if constexpr (PREPPED) {
          vf = *(const v8s*)(Vfb + (size_t)nc * 512 + (size_t)l * 8);  // frag(ktab=0,nc)
        } else {
#pragma unroll
          for (int e = 0; e < 8; e++)
            vf[e] = (short)f2bf(Vf[((size_t)bh * NN + hi * 8 + e) * DD + nc * 32 + m]);
        }
        oa[nc] = __builtin_amdgcn_mfma_f32_32x32x16_bf16(pa, vf, oa[nc], 0, 0, 0);
      }
    }

    // ---- main loop: teams on interleaved tiles, equal barrier counts ----
    for (int it = 0; it < T; ++it) {
      const int kb = kb_lo + (2 * it + team) * KT;
      const bool act = kb < kb_hi;
      __syncthreads();  // prev tile's Kl reads complete (and merge-reads, ji>0)
      if (act) {
#pragma unroll
        for (int i = 0; i < 8; i++)
          *(v8s*)(Kl[team] + (wv * 8 + i) * 512 + l * 8) = kst[i];
      }
      __syncthreads();  // staging visible
      if (!act) continue;
      if (kb + 2 * KT < kb_hi) stage_load(kb + 2 * KT);  // prefetch, 2-tile dist

#pragma unroll
      for (int ct = 0; ct < 2; ct++) {
        // V B-frags: coalesced 1KB global loads, consumed after QK+softmax
        v8s vf[8];
        if constexpr (PREPPED) {
#pragma unroll
          for (int i = 0; i < 8; i++) {
            const int ktl = i >> 2, nc = i & 3;
            vf[i] = *(const v8s*)(Vfb + ((size_t)((kb >> 4) + ct * 2 + ktl) * 4 + nc) * 512 + (size_t)l * 8);
          }
        } else {
#pragma unroll
          for (int i = 0; i < 8; i++) {
            const int ktl = i >> 2, nc = i & 3;
#pragma unroll
            for (int e = 0; e < 8; e++)
              vf[i][e] = (short)f2bf(Vf[((size_t)bh * NN + kb + (ct * 2 + ktl) * 16 + hi * 8 + e) * DD + nc * 32 + m]);
          }
        }

        // S^T(32x32): lane holds col q=qi, rows key = kb+ct*32+(reg&3)+8*(reg>>2)+rbase
        v16f s = (v16f)(0.f);
        __builtin_amdgcn_s_setprio(1);
#pragma unroll
        for (int kc = 0; kc < 8; kc++) {
          v8s kfr = *(const v8s*)(Kl[team] + (ct * 8 + kc) * 512 + l * 8);
          s = __builtin_amdgcn_mfma_f32_32x32x16_bf16(kfr, qf[kc], s, 0, 0, 0);
        }
        __builtin_amdgcn_s_setprio(0);

        const int kbct = kb + ct * 32;
        const bool full = (kbct + 31 <= qrow0w) && (kbct >= qrow0w + 32 - win);
        if (full) {
#pragma unroll
          for (int reg = 0; reg < 16; reg++) s[reg] = __builtin_amdgcn_exp2f(s[reg]);
        } else {
#pragma unroll
          for (int reg = 0; reg < 16; reg++) {
            const int kj = kbct + (reg & 3) + 8 * (reg >> 2) + rbase;
            const bool valid = (kj <= qi) && ((kj < ns) || (qi - kj < win));
            s[reg] = valid ? __builtin_amdgcn_exp2f(s[reg]) : 0.f;
          }
        }
        lsum += (((s[0] + s[1]) + (s[2] + s[3])) + ((s[4] + s[5]) + (s[6] + s[7])))
              + (((s[8] + s[9]) + (s[10] + s[11])) + ((s[12] + s[13]) + (s[14] + s[15])));

        // P -> A-frags in registers (no LDS)
        v8s pa0 = mkpa(s[0], s[1], s[2], s[3], s[4], s[5], s[6], s[7]);
        v8s pa1 = mkpa(s[8], s[9], s[10], s[11], s[12], s[13], s[14], s[15]);

        __builtin_amdgcn_s_setprio(1);
#pragma unroll
        for (int ktl = 0; ktl < 2; ktl++) {
          const v8s pf = ktl ? pa1 : pa0;
#pragma unroll
          for (int nc = 0; nc < 4; nc++)
            oa[nc] = __builtin_amdgcn_mfma_f32_32x32x16_bf16(pf, vf[ktl * 4 + nc], oa[nc], 0, 0, 0);
        }
        __builtin_amdgcn_s_setprio(0);
      }
    }

    // ---- merge team partials in LDS (reuse Kl as 32KB f32 scratch) ----
    __syncthreads();  // everyone done with Kl
    float* ex = (float*)&Kl[0][0];
    if (team == 1) {
#pragma unroll
      for (int nc = 0; nc < 4; nc++)
#pragma unroll
        for (int reg = 0; reg < 16; reg++)
          ex[(nc * 16 + reg) * 128 + wv * 64 + l] = oa[nc][reg];
      Ls[wv * 64 + l] = lsum;
    }
    __syncthreads();
    if (team == 0) {
#pragma unroll
      for (int nc = 0; nc < 4; nc++)
#pragma unroll
        for (int reg = 0; reg < 16; reg++)
          oa[nc][reg] += ex[(nc * 16 + reg) * 128 + wv * 64 + l];
      float lt = lsum + Ls[wv * 64 + l];
      lt += __shfl_xor(lt, 32, 64);
      const float inv = 1.f / lt;
      float* ob = O + ((size_t)bh * NN + qrow0w) * DD;
#pragma unroll
      for (int reg = 0; reg < 16; reg++) {
        const int row = (reg & 3) + 8 * (reg >> 2) + rbase;
        const float iv = __shfl(inv, row, 64);  // lane 'row' holds q=qrow0w+row
#pragma unroll
        for (int nc = 0; nc < 4; nc++)
          ob[(size_t)row * DD + nc * 32 + m] = oa[nc][reg] * iv;
      }
    }
    // next ji: loop-head __syncthreads orders team0's ex reads before reuse
  }
}

extern "C" void kernel_launch(void* const* d_in, const int* in_sizes, int n_in,
                              void* d_out, int out_size, void* d_ws, size_t ws_size,
                              hipStream_t stream) {
  const float* q = (const float*)d_in[0];
  const float* k = (const float*)d_in[1];
  const float* v = (const float*)d_in[2];
  const int* nsp = (const int*)d_in[3];
  const int* wsp = (const int*)d_in[4];
  float* out = (float*)d_out;

  const size_t half = (size_t)BHH * NN * DD * sizeof(unsigned short);  // 16 MiB
  const int nblocks = BHH * 24;  // uniform 17-unit jobs

  if (ws_size >= 2 * half) {
    unsigned short* kbf = (unsigned short*)d_ws;
    unsigned short* vfrag = (unsigned short*)((char*)d_ws + half);
    prep<<<dim3(32, 2, 2 * BHH), 256, 0, stream>>>(k, v, kbf, vfrag);
    attn<true><<<nblocks, 256, 0, stream>>>(q, k, kbf, vfrag, v, nsp, wsp, out);
  } else {
    attn<false><<<nblocks, 256, 0, stream>>>(q, k, nullptr, nullptr, v, nsp, wsp, out);
  }
}

// Round 6
// 190.957 us; speedup vs baseline: 1.0946x; 1.0946x over previous
//
#include <hip/hip_runtime.h>
#include <stdint.h>

// Problem constants (fixed by setup_inputs: B=2,H=16,N=2048,D=128), f32 in/out.
#define NN 2048
#define DD 128
#define BHH 32
#define QT 64   // queries per block (32 per wave x 2 waves)
#define KT 64   // keys per K tile

typedef short v8s __attribute__((ext_vector_type(8)));   // 8 bf16 (raw bits)
typedef short v4s __attribute__((ext_vector_type(4)));   // 4 bf16
typedef float v4f __attribute__((ext_vector_type(4)));
typedef float v16f __attribute__((ext_vector_type(16)));
typedef unsigned int u32;
typedef u32 u32x2 __attribute__((ext_vector_type(2)));
typedef u32 u32x4 __attribute__((ext_vector_type(4)));

__device__ __forceinline__ unsigned short f2bf(float x) {
  unsigned u = __builtin_bit_cast(unsigned, x);
  u += 0x7fffu + ((u >> 16) & 1u);   // RNE
  return (unsigned short)(u >> 16);
}

__device__ __forceinline__ v8s cvt8(const float* __restrict__ p) {
  v8s r;
#pragma unroll
  for (int j = 0; j < 8; j++) r[j] = (short)f2bf(p[j]);
  return r;
}

// v_cvt_pk_bf16_f32: 2 f32 -> packed 2x bf16 (RNE), single VALU op.
__device__ __forceinline__ u32 pk2(float a, float b) {
  u32 r;
  asm("v_cvt_pk_bf16_f32 %0, %1, %2" : "=v"(r) : "v"(a), "v"(b));
  return r;
}

// async global->LDS DMA, 16B/lane: LDS dst is wave-uniform base + lane*16,
// global src is per-lane (guide §5, m97-verified usage from plain HIP).
__device__ __forceinline__ void gl_lds16(const unsigned short* g, unsigned short* l) {
  __builtin_amdgcn_global_load_lds((const unsigned int*)g, (unsigned int*)l, 16, 0, 0);
}

// Fused prep, one dispatch. grid=(32,2,64):
//  z >= 32: Kfrag pack: frag(kb32,kc) lane l elem j = K[kb32*32+(l&31)][kc*16+(l>>5)*8+j]
//           (1KB frags -> attn K staging is contiguous global_load_lds)
//  z <  32: Vfrag pack (r5-verified): frag(kt16,nc) lane l elem j
//           = V[kt16*16+(l>>5)*8+j][nc*32+(l&31)]
__global__ __launch_bounds__(256) void prep(const float* __restrict__ K, const float* __restrict__ V,
                     unsigned short* __restrict__ Kb, unsigned short* __restrict__ Vt) {
  const int z = blockIdx.z;
  const int tid = threadIdx.x;
  if (z >= BHH) {
    // ---- K fragment pack ----
    const int bh = z - BHH;
    const int kb32 = blockIdx.y * 32 + blockIdx.x;   // 0..63 (32-key block)
    const int m = tid & 31, kc = tid >> 5;           // kc 0..7
    const float* src = K + ((size_t)bh * NN + kb32 * 32 + m) * DD + kc * 16;
    v4f a0 = *(const v4f*)(src);
    v4f a1 = *(const v4f*)(src + 4);
    v4f a2 = *(const v4f*)(src + 8);
    v4f a3 = *(const v4f*)(src + 12);
    u32x4 w0 = { pk2(a0[0], a0[1]), pk2(a0[2], a0[3]), pk2(a1[0], a1[1]), pk2(a1[2], a1[3]) };
    u32x4 w1 = { pk2(a2[0], a2[1]), pk2(a2[2], a2[3]), pk2(a3[0], a3[1]), pk2(a3[2], a3[3]) };
    unsigned short* base = Kb + (((size_t)bh * 64 + kb32) * 8 + kc) * 512;
    *(u32x4*)(base + (size_t)m * 8) = w0;          // hi=0 lanes (cols kc*16+0..7)
    *(u32x4*)(base + (size_t)(32 + m) * 8) = w1;   // hi=1 lanes (cols kc*16+8..15)
    return;
  }
  // ---- V fragment pack (r5-verified) ----
  __shared__ __align__(16) unsigned short t[64 * 68];  // [dloc][nloc], stride 68
  const int bh = z;
  const int n0b = blockIdx.x, d0b = blockIdx.y;        // 64-blocks
  const int c16 = tid & 15, r4 = tid >> 4;
  const float* src = V + ((size_t)bh * NN + n0b * 64 + r4 * 4) * DD + d0b * 64 + c16 * 4;
  v4f f0 = *(const v4f*)(src);
  v4f f1 = *(const v4f*)(src + DD);
  v4f f2 = *(const v4f*)(src + 2 * DD);
  v4f f3 = *(const v4f*)(src + 3 * DD);
#pragma unroll
  for (int j = 0; j < 4; j++) {
    u32x2 w = { pk2(f0[j], f1[j]), pk2(f2[j], f3[j]) };   // n-order r4*4..+3
    *(u32x2*)(t + (c16 * 4 + j) * 68 + r4 * 4) = w;       // t[d][n] = V[n][d]
  }
  __syncthreads();
  unsigned short* Vfb = Vt + (size_t)bh * (512u * 512);   // 128*4*512 shorts/bh
#pragma unroll
  for (int p = 0; p < 2; p++) {
    const int fid = p * 4 + (tid >> 6);       // 0..7
    const int ktl = fid >> 1, ncl = fid & 1;
    const int lane = tid & 63;
    const int dloc = ncl * 32 + (lane & 31);
    const int nloc = ktl * 16 + (lane >> 5) * 8;
    v4s x0 = *(const v4s*)(t + dloc * 68 + nloc);
    v4s x1 = *(const v4s*)(t + dloc * 68 + nloc + 4);
    v8s o = { x0[0], x0[1], x0[2], x0[3], x1[0], x1[1], x1[2], x1[3] };
    const size_t fi = (size_t)(n0b * 4 + ktl) * 4 + (d0b * 2 + ncl);
    *(v8s*)(Vfb + fi * 512 + (size_t)lane * 8) = o;
  }
}

// Flash-style sink+sliding-window attention, f32 in/out, bf16 MFMA compute.
// R6 theory: r0-r5 all pinned at ~80us (11.3k cyc per 64x64 tile-unit vs
// ~1.5k compute chain) because (a) scattered staging addresses saturate the
// TA request pipe (~512 reqs/wave-unit ~ 0.8 req/cyc/CU) and (b) r4's
// prefetch regs exceeded the 128-VGPR choice -> compiler sank the loads,
// exposing full latency per tile. Fix both:
//  - ALL hot loads contiguous 1KB frag loads (Kfrag/Vfrag from prep).
//  - K: LDS double-buffer (2x16KB) via global_load_lds DMA: zero VGPR cost,
//    issued at tile top, can't be sunk. ONE barrier per tile.
//  - V: registers only; 16 contiguous frag loads at tile start, consumed
//    after QK+softmax (~700cyc later, T14).
//  - amdgpu_waves_per_eu(1,2): 256-VGPR budget (grid caps at 1.5 waves/SIMD
//    anyway), so the compiler keeps the schedule instead of shrinking regs.
// Verified pieces kept from r4/r5 (both PASSED): swapped-QK 32x32 fragment
// mappings, mask + full-tile fast path, cvt_pk+permlane32_swap P-pack,
// sink16 tile, job set (24/bh x 17 units), XCD mapping, epilogue.
// mfma_f32_32x32x16_bf16 layouts: A: lane holds A[m=lane&31][k=(lane>>5)*8+j]
// B: B[k=(lane>>5)*8+j][n=lane&31]; C/D: D[row=(reg&3)+8*(reg>>2)+4*(lane>>5)]
// [col=lane&31]  (m74/m101-verified mapping).
template <bool PREPPED>
__global__ __launch_bounds__(128) __attribute__((amdgpu_waves_per_eu(1, 2)))
void attn(
    const float* __restrict__ Q,
    const float* __restrict__ Kf, const unsigned short* __restrict__ Kb,
    const unsigned short* __restrict__ Vfr, const float* __restrict__ Vf,
    const int* __restrict__ nsp, const int* __restrict__ wsp,
    float* __restrict__ O) {
  const int ns = nsp[0], win = wsp[0];
  const int x = blockIdx.x;              // 0..767
  const int xcd = x & 7, slot = x >> 3;  // slot 0..95
  const int bh = xcd + 8 * (slot / 24);
  const int jobid = slot % 24;           // 0..23
  int qis[2], njobs;
  if (jobid < 16) { njobs = 1; qis[0] = 31 - jobid; qis[1] = 0; }
  else { int p = jobid - 16; njobs = 2; qis[0] = 15 - p; qis[1] = p; }

  const int tid = threadIdx.x;
  const int w = tid >> 6;      // wave 0..1 (q rows w*32..+31 of the job)
  const int l = tid & 63;
  const int m = l & 31;
  const int hi = l >> 5;
  const int rbase = 4 * hi;

  __shared__ __align__(16) unsigned short Kl[2][16 * 512];  // 2 x 16KB dbuf

  const float csc = 0.088388347648318447f * 1.4426950408889634f;  // 1/sqrt(128)*log2(e)

  const unsigned short* Vfb = Vfr + (size_t)bh * (512u * 512);

  // P C-layout -> PV A-frag via cvt_pk + permlane32_swap (r4-verified)
  auto mkpa = [&](float a0, float a1, float a2, float a3,
                  float b0, float b1, float b2, float b3) -> v8s {
    u32x2 r02 = __builtin_amdgcn_permlane32_swap(pk2(a0, a1), pk2(b0, b1), false, false);
    u32x2 r13 = __builtin_amdgcn_permlane32_swap(pk2(a2, a3), pk2(b2, b3), false, false);
    u32x4 pw = { r02[0], r13[0], r02[1], r13[1] };
    return __builtin_bit_cast(v8s, pw);
  };

  for (int ji = 0; ji < njobs; ji++) {
    const int q0 = qis[ji] * QT;
    const int qrow0w = q0 + w * 32;  // this wave's 32 query rows
    const int qi = qrow0w + m;       // this lane's query (S^T col)

    // Q B-frags, pre-scaled: lane holds Q[qi][kc*16 + hi*8 + j]*csc
    v8s qf[8];
    {
      const float* qb = Q + ((size_t)bh * NN + qi) * DD + hi * 8;
#pragma unroll
      for (int kc = 0; kc < 8; kc++) {
        v4f a = *(const v4f*)(qb + kc * 16);
        v4f b = *(const v4f*)(qb + kc * 16 + 4);
        u32x4 pw = { pk2(a[0] * csc, a[1] * csc), pk2(a[2] * csc, a[3] * csc),
                     pk2(b[0] * csc, b[1] * csc), pk2(b[2] * csc, b[3] * csc) };
        qf[kc] = __builtin_bit_cast(v8s, pw);
      }
    }

    float lsum = 0.f;
    v16f oa[4];
#pragma unroll
    for (int nc = 0; nc < 4; nc++) oa[nc] = (v16f)(0.f);

    // ---- tile range (contiguous, r3-verified) ----
    const int wstart = q0 - win + 1;
    const bool sink16 = (wstart > KT - 1) && (ns <= 16);
    const int kb_lo = sink16 ? ((wstart >> 6) << 6) : 0;
    const int kb_hi = q0 + QT;

    if constexpr (PREPPED) {
      // issue this wave's 8 K-frags (ct=w half of the tile) via DMA
      auto issueK = [&](int kb, int buf) {
        const unsigned short* src =
            Kb + (((size_t)bh * 64 + (kb >> 5) + w) * 8) * 512 + (size_t)l * 8;
        unsigned short* dst = &Kl[buf][(w * 8) * 512];
#pragma unroll
        for (int i = 0; i < 8; i++)
          gl_lds16(src + (size_t)i * 512, dst + i * 512);
      };

      int cur = 0;
      issueK(kb_lo, 0);  // prologue: tile0 DMA in flight during sink compute

      if (sink16) {
        // sink tile: keys 0..31 in one 32x32 block (keys >= ns masked);
        // contiguous frag loads (kb32=0 frags, ktab=0 V frags)
        v8s kf0[8];
#pragma unroll
        for (int kc = 0; kc < 8; kc++)
          kf0[kc] = *(const v8s*)(Kb + ((size_t)bh * 64 * 8 + kc) * 512 + (size_t)l * 8);
        v16f s = (v16f)(0.f);
#pragma unroll
        for (int kc = 0; kc < 8; kc++)
          s = __builtin_amdgcn_mfma_f32_32x32x16_bf16(kf0[kc], qf[kc], s, 0, 0, 0);
#pragma unroll
        for (int reg = 0; reg < 16; reg++) {
          const int kj = (reg & 3) + 8 * (reg >> 2) + rbase;
          const bool valid = (kj < ns) && (kj <= qi);
          s[reg] = valid ? __builtin_amdgcn_exp2f(s[reg]) : 0.f;
        }
        lsum += (((s[0] + s[1]) + (s[2] + s[3])) + ((s[4] + s[5]) + (s[6] + s[7])))
              + (((s[8] + s[9]) + (s[10] + s[11])) + ((s[12] + s[13]) + (s[14] + s[15])));
        v8s pa = mkpa(s[0], s[1], s[2], s[3], s[4], s[5], s[6], s[7]);
#pragma unroll
        for (int nc = 0; nc < 4; nc++) {
          v8s vf = *(const v8s*)(Vfb + (size_t)nc * 512 + (size_t)l * 8);
          oa[nc] = __builtin_amdgcn_mfma_f32_32x32x16_bf16(pa, vf, oa[nc], 0, 0, 0);
        }
      }

      asm volatile("s_waitcnt vmcnt(0)" ::: "memory");
      __syncthreads();  // tile0 staged (both waves' DMA landed)

      for (int kb = kb_lo; kb < kb_hi; kb += KT) {
        if (kb + KT < kb_hi) issueK(kb + KT, cur ^ 1);  // 0-reg prefetch DMA
        // V frags for this tile: 16 contiguous 1KB loads, consumed after QK+SM
        v8s vf[16];
#pragma unroll
        for (int i = 0; i < 16; i++) {
          const int kt = i >> 2, nc = i & 3;
          vf[i] = *(const v8s*)(Vfb + ((size_t)((kb >> 4) + kt) * 4 + nc) * 512 + (size_t)l * 8);
        }

#pragma unroll
        for (int ct = 0; ct < 2; ct++) {
          // S^T(32x32): lane holds col q=qi, rows key = kb+ct*32+(reg&3)+8*(reg>>2)+rbase
          v16f s = (v16f)(0.f);
          __builtin_amdgcn_s_setprio(1);
#pragma unroll
          for (int kc = 0; kc < 8; kc++) {
            v8s kfr = *(const v8s*)(&Kl[cur][(ct * 8 + kc) * 512 + l * 8]);
            s = __builtin_amdgcn_mfma_f32_32x32x16_bf16(kfr, qf[kc], s, 0, 0, 0);
          }
          __builtin_amdgcn_s_setprio(0);

          const int kbct = kb + ct * 32;
          const bool full = (kbct + 31 <= qrow0w) && (kbct >= qrow0w + 32 - win);
          if (full) {
#pragma unroll
            for (int reg = 0; reg < 16; reg++) s[reg] = __builtin_amdgcn_exp2f(s[reg]);
          } else {
#pragma unroll
            for (int reg = 0; reg < 16; reg++) {
              const int kj = kbct + (reg & 3) + 8 * (reg >> 2) + rbase;
              const bool valid = (kj <= qi) && ((kj < ns) || (qi - kj < win));
              s[reg] = valid ? __builtin_amdgcn_exp2f(s[reg]) : 0.f;
            }
          }
          lsum += (((s[0] + s[1]) + (s[2] + s[3])) + ((s[4] + s[5]) + (s[6] + s[7])))
                + (((s[8] + s[9]) + (s[10] + s[11])) + ((s[12] + s[13]) + (s[14] + s[15])));

          v8s pa0 = mkpa(s[0], s[1], s[2], s[3], s[4], s[5], s[6], s[7]);
          v8s pa1 = mkpa(s[8], s[9], s[10], s[11], s[12], s[13], s[14], s[15]);

          __builtin_amdgcn_s_setprio(1);
#pragma unroll
          for (int ktl = 0; ktl < 2; ktl++) {
            const v8s pf = ktl ? pa1 : pa0;
#pragma unroll
            for (int nc = 0; nc < 4; nc++)
              oa[nc] = __builtin_amdgcn_mfma_f32_32x32x16_bf16(pf, vf[(ct * 2 + ktl) * 4 + nc],
                                                               oa[nc], 0, 0, 0);
          }
          __builtin_amdgcn_s_setprio(0);
        }

        asm volatile("s_waitcnt vmcnt(0)" ::: "memory");  // next-tile DMA landed
        __syncthreads();  // both waves done with Kl[cur]; Kl[cur^1] visible
        cur ^= 1;
      }
    } else {
      // fallback (no workspace): direct-global with on-the-fly cvt; slow path
      for (int kb = 0; kb < kb_hi; kb += KT) {
        if ((kb >= ns) && (kb + KT - 1 < wstart)) continue;
#pragma unroll
        for (int ct = 0; ct < 2; ct++) {
          v16f s = (v16f)(0.f);
#pragma unroll
          for (int kc = 0; kc < 8; kc++) {
            v8s kfr = cvt8(Kf + ((size_t)bh * NN + kb + ct * 32 + m) * DD + kc * 16 + hi * 8);
            s = __builtin_amdgcn_mfma_f32_32x32x16_bf16(kfr, qf[kc], s, 0, 0, 0);
          }
#pragma unroll
          for (int reg = 0; reg < 16; reg++) {
            const int kj = kb + ct * 32 + (reg & 3) + 8 * (reg >> 2) + rbase;
            const bool valid = (kj <= qi) && ((kj < ns) || (qi - kj < win));
            s[reg] = valid ? __builtin_amdgcn_exp2f(s[reg]) : 0.f;
            lsum += s[reg];
          }
          v8s pa0 = mkpa(s[0], s[1], s[2], s[3], s[4], s[5], s[6], s[7]);
          v8s pa1 = mkpa(s[8], s[9], s[10], s[11], s[12], s[13], s[14], s[15]);
#pragma unroll
          for (int ktl = 0; ktl < 2; ktl++) {
            const v8s pf = ktl ? pa1 : pa0;
#pragma unroll
            for (int nc = 0; nc < 4; nc++) {
              v8s vfe;
#pragma unroll
              for (int e = 0; e < 8; e++)
                vfe[e] = (short)f2bf(Vf[((size_t)bh * NN + kb + (ct * 2 + ktl) * 16 + hi * 8 + e) * DD + nc * 32 + m]);
              oa[nc] = __builtin_amdgcn_mfma_f32_32x32x16_bf16(pf, vfe, oa[nc], 0, 0, 0);
            }
          }
        }
      }
    }

    // epilogue (r4-verified): lane holds lsum partial for q=qi over its key-half
    float lt = lsum + __shfl_xor(lsum, 32, 64);
    const float inv = 1.f / lt;
    float* ob = O + ((size_t)bh * NN + qrow0w) * DD;
#pragma unroll
    for (int reg = 0; reg < 16; reg++) {
      const int row = (reg & 3) + 8 * (reg >> 2) + rbase;
      const float iv = __shfl(inv, row, 64);   // lane 'row' holds q=qrow0w+row
#pragma unroll
      for (int nc = 0; nc < 4; nc++)
        ob[(size_t)row * DD + nc * 32 + m] = oa[nc][reg] * iv;
    }
  }
}

extern "C" void kernel_launch(void* const* d_in, const int* in_sizes, int n_in,
                              void* d_out, int out_size, void* d_ws, size_t ws_size,
                              hipStream_t stream) {
  const float* q = (const float*)d_in[0];
  const float* k = (const float*)d_in[1];
  const float* v = (const float*)d_in[2];
  const int* nsp = (const int*)d_in[3];
  const int* wsp = (const int*)d_in[4];
  float* out = (float*)d_out;

  const size_t half = (size_t)BHH * NN * DD * sizeof(unsigned short);  // 16 MiB
  const int nblocks = BHH * 24;  // uniform 17-unit jobs

  if (ws_size >= 2 * half) {
    unsigned short* kfrag = (unsigned short*)d_ws;
    unsigned short* vfrag = (unsigned short*)((char*)d_ws + half);
    prep<<<dim3(32, 2, 2 * BHH), 256, 0, stream>>>(k, v, kfrag, vfrag);
    attn<true><<<nblocks, 128, 0, stream>>>(q, k, kfrag, vfrag, v, nsp, wsp, out);
  } else {
    attn<false><<<nblocks, 128, 0, stream>>>(q, k, nullptr, nullptr, v, nsp, wsp, out);
  }
}